// Round 17
// baseline (339.933 us; speedup 1.0000x reference)
//
#include <hip/hip_runtime.h>
#include <hip/hip_bf16.h>
#include <stdint.h>

// B=32, S=4096, ENC=512, DEC=512
// out = softmax_s( sum_d tanh( enc @ W_e^T + dh @ W_h^T + b ) * v )

typedef __attribute__((ext_vector_type(8))) short short8;
typedef __attribute__((ext_vector_type(4))) float f32x4;

static __device__ __forceinline__ short8 cvt8(float4 a, float4 b) {
    // 4x v_cvt_pk_bf16_f32 (RNE)
    union { short8 s; __hip_bfloat162 h[4]; } u;
    u.h[0] = __float22bfloat162_rn(float2{a.x, a.y});
    u.h[1] = __float22bfloat162_rn(float2{a.z, a.w});
    u.h[2] = __float22bfloat162_rn(float2{b.x, b.y});
    u.h[3] = __float22bfloat162_rn(float2{b.z, b.w});
    return u.s;
}

static __device__ __forceinline__ float tanh_fast(float x) {
    // tanh(x) = 1 - 2/(exp(2x)+1); overflow->+1, underflow->-1 (both correct)
    return 1.0f - 2.0f / (__expf(2.0f * x) + 1.0f);
}

// ---------------------------------------------------------------------------
// Kernel 1 (96 blocks x 512):
//   blocks 0..63 : W_e (= W_attn[:,512:]) -> bf16 into wsB, layout
//     [cb(4)][half(2)][c(128)][slot(32)] x 16B where chunk content =
//     W_e[cb*128 + c][half*256 + (slot^(c&7))*8 .. +8]   (pre-swizzled so
//     the fused kernel global_load_lds's LINEARLY; frag read at slot
//     (wk*16+ks*4+lhi)^(llo&7) is conflict-free -- proven swizzle family).
//   blocks 64..95: proj1[b][e] = sum_d dh[b,d]*W_attn[e,d] + b_attn[e]
// ---------------------------------------------------------------------------
__global__ __launch_bounds__(512) void prep_kernel(
    const float* __restrict__ dh, const float* __restrict__ W_attn,
    const float* __restrict__ b_attn, unsigned short* __restrict__ wsB,
    float* __restrict__ wsP1) {
    __shared__ float dhs[512];
    const int tid = threadIdx.x;
    if (blockIdx.x < 64) {
        int idx  = blockIdx.x * 512 + tid;      // 0..32767 16B-chunks
        int slot = idx & 31;
        int c    = (idx >> 5) & 127;
        int half = (idx >> 12) & 1;
        int cbb  = idx >> 13;                   // 0..3
        int u    = slot ^ (c & 7);
        const float* src = W_attn + (size_t)(cbb * 128 + c) * 1024 + 512 +
                           half * 256 + u * 8;
        float4 f0 = *(const float4*)(src);
        float4 f1 = *(const float4*)(src + 4);
        *(short8*)((char*)wsB + (size_t)idx * 16) = cvt8(f0, f1);
    } else {
        int b = blockIdx.x - 64;
        dhs[tid] = dh[b * 512 + tid];
        __syncthreads();
        const float* wrow = W_attn + (size_t)tid * 1024;  // W_h row e=tid
        float acc = 0.f;
        #pragma unroll 8
        for (int d = 0; d < 512; d += 4) {
            float4 w = *(const float4*)(wrow + d);
            acc += dhs[d] * w.x + dhs[d + 1] * w.y + dhs[d + 2] * w.z + dhs[d + 3] * w.w;
        }
        wsP1[b * 512 + tid] = acc + b_attn[tid];
    }
}

// ---------------------------------------------------------------------------
// Kernel 2: K-SPLIT barrier-free fused GEMM. Block = 64 rows x 128 cols
// (cb quarter of N=512), K=512. 512 thr = 8 waves (wm2 x wn2 x wk2):
// wave tile 32 rows x 64 cols x K=128-per-half (acc[2][4] = 32 regs).
//   - B: 64 KB LDS per K-half, staged ONCE per half via global_load_lds
//     from pre-swizzled wsB -> 4 barriers per block TOTAL.
//   - A: direct global->reg f32 + cvt_pk; each wave's (rows x k) slice is
//     EXCLUSIVE within the block (wk-split) -> no convoy, no ds_write.
//   - free-run: 32 MFMAs/wave/half with zero fences; 16 waves/CU
//     (4/SIMD, 2 blocks/CU) hide each other's latencies.
// R16 BUG FIX: B slot index now includes the wave's K-split offset (wk*16
// slots = wk*128 k). R16 had wk=1 waves reading B[k=0..127] against
// A[k=128..255] -> absmax 1.4e-3. One-line fix, all else identical.
// K-partials combined via LDS exchange (B region, dead); tanh+v-dot
// epilogue on wk=0 waves; cb partials summed in softmax.
// ---------------------------------------------------------------------------
__global__ __launch_bounds__(512, 4) void fused_kernel(
    const float* __restrict__ enc, const unsigned short* __restrict__ wsB,
    const float* __restrict__ wsP1, const float* __restrict__ vvec,
    float* __restrict__ out, float* __restrict__ wsS) {
    __shared__ char lds[65536];                  // B half-panel / exch+red

    const int tid  = threadIdx.x;
    const int wave = tid >> 6;
    const int lane = tid & 63;
    const int llo  = lane & 15, lhi = lane >> 4;
    const int wk   = wave & 1, wn = (wave >> 1) & 1, wm = wave >> 2;

    // XCD-chunked bijective swizzle (8192 % 8 == 0): the 4 cb-partners of an
    // M-tile are 8/16/24 apart in blockIdx -> same XCD -> enc L2/L1-hot.
    const int bid = blockIdx.x;
    const int lb  = (bid & 7) * 1024 + (bid >> 3);
    const int rb  = lb >> 2, cb = lb & 3;
    const int m0  = rb * 64;
    const int b   = m0 >> 12;                    // batch (64 | 4096)

    // A-direct: lane(llo,lhi), frag mi, ksub reads
    // enc[m0 + wm*32 + mi*16 + llo][half*256 + wk*128 + ks*32 + lhi*8 .. +8]
    const float* abase = enc + (size_t)(m0 + wm * 32 + llo) * 512 + wk * 128 + lhi * 8;

    // B LDS: [c(128)][slot(32)]x16B, swizzled; c&7 == llo&7 for our reads.
    const int bsw = llo & 7;
    int bb[4];
    #pragma unroll
    for (int ni = 0; ni < 4; ++ni)
        bb[ni] = (wn * 64 + ni * 16 + llo) * 512;

    f32x4 acc[2][4] = {};

    #pragma unroll
    for (int half = 0; half < 2; ++half) {
        // ---- stage B half-panel (linear glds from pre-swizzled source) ----
        const char* bsrc = (const char*)wsB + (size_t)(cb * 2 + half) * 65536;
        #pragma unroll
        for (int r = 0; r < 8; ++r) {
            int off = (r * 512 + tid) * 16;
            __builtin_amdgcn_global_load_lds(
                (const uint32_t __attribute__((address_space(1)))*)(bsrc + off),
                (uint32_t __attribute__((address_space(3)))*)(lds + off),
                16, 0, 0);
        }
        __syncthreads();   // B half ready (drains glds)

        // ---- free-run: 4 ksubs, no fences, compiler pipelines freely ----
        #pragma unroll
        for (int ks = 0; ks < 4; ++ks) {
            const float* ap = abase + half * 256 + ks * 32;
            float4 a00 = *(const float4*)(ap);
            float4 a01 = *(const float4*)(ap + 4);
            float4 a10 = *(const float4*)(ap + 8192);       // +16 rows
            float4 a11 = *(const float4*)(ap + 8196);
            // slot = (wk*16 + ks*4 + lhi) ^ (c&7): covers this wave's k range
            const int so = (((wk << 4) + ks * 4 + lhi) ^ bsw) * 16;
            short8 bf0 = *(const short8*)(lds + bb[0] + so);
            short8 bf1 = *(const short8*)(lds + bb[1] + so);
            short8 bf2 = *(const short8*)(lds + bb[2] + so);
            short8 bf3 = *(const short8*)(lds + bb[3] + so);
            short8 af0 = cvt8(a00, a01);
            short8 af1 = cvt8(a10, a11);
            acc[0][0] = __builtin_amdgcn_mfma_f32_16x16x32_bf16(af0, bf0, acc[0][0], 0, 0, 0);
            acc[0][1] = __builtin_amdgcn_mfma_f32_16x16x32_bf16(af0, bf1, acc[0][1], 0, 0, 0);
            acc[0][2] = __builtin_amdgcn_mfma_f32_16x16x32_bf16(af0, bf2, acc[0][2], 0, 0, 0);
            acc[0][3] = __builtin_amdgcn_mfma_f32_16x16x32_bf16(af0, bf3, acc[0][3], 0, 0, 0);
            acc[1][0] = __builtin_amdgcn_mfma_f32_16x16x32_bf16(af1, bf0, acc[1][0], 0, 0, 0);
            acc[1][1] = __builtin_amdgcn_mfma_f32_16x16x32_bf16(af1, bf1, acc[1][1], 0, 0, 0);
            acc[1][2] = __builtin_amdgcn_mfma_f32_16x16x32_bf16(af1, bf2, acc[1][2], 0, 0, 0);
            acc[1][3] = __builtin_amdgcn_mfma_f32_16x16x32_bf16(af1, bf3, acc[1][3], 0, 0, 0);
        }
        __syncthreads();   // all waves done with this B half
    }

    // ---- K-reduce across wk pairs via LDS (B region is dead) ----
    float* exch = (float*)lds;                   // 4 pids x 2048 f32 = 32 KB
    float* red2 = (float*)(lds + 32768);         // 128 f32
    const int pid = wm * 2 + wn;
    if (wk) {
        #pragma unroll
        for (int mi = 0; mi < 2; ++mi)
            #pragma unroll
            for (int ni = 0; ni < 4; ++ni)
                #pragma unroll
                for (int r = 0; r < 4; ++r)
                    exch[pid * 2048 + ((mi * 4 + ni) * 4 + r) * 64 + lane] = acc[mi][ni][r];
    }
    __syncthreads();
    if (!wk) {
        float p1v[4], vv[4];
        #pragma unroll
        for (int ni = 0; ni < 4; ++ni) {
            int d = cb * 128 + wn * 64 + ni * 16 + llo;
            p1v[ni] = wsP1[b * 512 + d];
            vv[ni]  = vvec[d];
        }
        float part[8];
        #pragma unroll
        for (int mi = 0; mi < 2; ++mi)
            #pragma unroll
            for (int r = 0; r < 4; ++r) {
                float s = 0.f;
                #pragma unroll
                for (int ni = 0; ni < 4; ++ni) {
                    float v = acc[mi][ni][r] +
                              exch[pid * 2048 + ((mi * 4 + ni) * 4 + r) * 64 + lane] +
                              p1v[ni];
                    s += tanh_fast(v) * vv[ni];
                }
                part[mi * 4 + r] = s;
            }
        #pragma unroll
        for (int off = 1; off < 16; off <<= 1)
            #pragma unroll
            for (int i = 0; i < 8; ++i)
                part[i] += __shfl_xor(part[i], off, 64);
        if (llo == 0) {
            #pragma unroll
            for (int mi = 0; mi < 2; ++mi)
                #pragma unroll
                for (int r = 0; r < 4; ++r)
                    red2[wn * 64 + wm * 32 + mi * 16 + lhi * 4 + r] = part[mi * 4 + r];
        }
    }
    __syncthreads();
    if (tid < 64) {
        float s = red2[tid] + red2[64 + tid];
        float* dst = (cb == 0) ? out : (wsS + (size_t)(cb - 1) * 131072);
        dst[m0 + tid] = s;
    }
}

// ---------------------------------------------------------------------------
// Kernel 3: sum the 4 column-quarter partials, row softmax over S=4096,
// write to out. 32 blocks x 256.
// ---------------------------------------------------------------------------
__global__ __launch_bounds__(256) void softmax_kernel(
    float* __restrict__ out, const float* __restrict__ wsS) {
    __shared__ float wred[8];
    const int b = blockIdx.x, tid = threadIdx.x;
    float* row = out + (size_t)b * 4096;
    const float* r1 = wsS + (size_t)b * 4096;
    const float* r2 = wsS + 131072 + (size_t)b * 4096;
    const float* r3 = wsS + 262144 + (size_t)b * 4096;
    float vals[16];
    float lmax = -1e30f;
    #pragma unroll
    for (int i = 0; i < 16; ++i) {
        int j = i * 256 + tid;
        vals[i] = row[j] + r1[j] + r2[j] + r3[j];
        lmax = fmaxf(lmax, vals[i]);
    }
    #pragma unroll
    for (int off = 32; off >= 1; off >>= 1)
        lmax = fmaxf(lmax, __shfl_xor(lmax, off, 64));
    if ((tid & 63) == 0) wred[tid >> 6] = lmax;
    __syncthreads();
    float gmax = fmaxf(fmaxf(wred[0], wred[1]), fmaxf(wred[2], wred[3]));
    float lsum = 0.f;
    #pragma unroll
    for (int i = 0; i < 16; ++i) {
        vals[i] = expf(vals[i] - gmax);
        lsum += vals[i];
    }
    #pragma unroll
    for (int off = 32; off >= 1; off >>= 1)
        lsum += __shfl_xor(lsum, off, 64);
    if ((tid & 63) == 0) wred[4 + (tid >> 6)] = lsum;
    __syncthreads();
    float inv = 1.f / (wred[4] + wred[5] + wred[6] + wred[7]);
    #pragma unroll
    for (int i = 0; i < 16; ++i)
        row[i * 256 + tid] = vals[i] * inv;
}

extern "C" void kernel_launch(void* const* d_in, const int* in_sizes, int n_in,
                              void* d_out, int out_size, void* d_ws, size_t ws_size,
                              hipStream_t stream) {
    const float* dh   = (const float*)d_in[0];   // (32, 512)
    const float* enc  = (const float*)d_in[1];   // (32, 4096, 512)
    const float* Wat  = (const float*)d_in[2];   // (512, 1024)
    const float* batt = (const float*)d_in[3];   // (512,)
    const float* vvec = (const float*)d_in[4];   // (512,)
    float* out = (float*)d_out;                  // (32, 4096)

    unsigned short* wsB = (unsigned short*)d_ws;               // 512 KB bf16 W_e
    float* wsP1 = (float*)((char*)d_ws + 524288);              // 64 KB proj1
    float* wsS  = (float*)((char*)d_ws + 589824);              // 3 x 512 KB partials

    hipLaunchKernelGGL(prep_kernel, dim3(96), dim3(512), 0, stream,
                       dh, Wat, batt, wsB, wsP1);
    hipLaunchKernelGGL(fused_kernel, dim3(8192), dim3(512), 0, stream,
                       enc, wsB, wsP1, vvec, out, wsS);
    hipLaunchKernelGGL(softmax_kernel, dim3(32), dim3(256), 0, stream, out, wsS);
}